// Round 12
// baseline (278.032 us; speedup 1.0000x reference)
//
#include <hip/hip_runtime.h>

// GraphSAGE 3-layer, N=50000, E=800000, D=128, D_OUT=64.
// R22 (266.9us): merged prep+bin; drain w/ inline CSR build; 8 dispatches.
// R23: XCD-staggered quarter order in the gathers. Gathers are the dominant
// remaining block (~100-150us of 267) and are L2-miss/L3-throughput-bound:
// src 12.8MB vs 4MB per-XCD L2. Quarter-keyed CSR gives 3.2MB col-slices;
// all nodes previously walked quarters 0->3 in lockstep so all 8 XCD L2s
// competed for the same slice. Now block starts at q0 = blockIdx.x & 3
// (XCD-affine): two contiguous ranges [q0,4) then [0,q0); each XCD L2 holds
// its own hot slice. Applied to gather_agg_bf and gather_out. fp-sum order
// change only (absmax margin is bf16-dominated). Neutral => L3-fabric-bound.

#define D 128
#define K2 256
#define NQ 4            // col quarters
#define QW 12500        // quarter width (N/4)
#define NBUCK 196       // row buckets (256 rows each)
#define SCAP 5120       // staging capacity per bucket (expected 4081, +16 sigma)
#define OCAP 8192       // overflow list capacity (never reached in practice)
#define CH 2048         // edges per scatter_bin block
#define BINBLK 391      // ceil(E/CH)
#define XBLK 3125       // 1.6M quads / 512
#define WBLK 160        // 81920 / 512

typedef __attribute__((ext_vector_type(8))) short short8;
typedef __attribute__((ext_vector_type(4))) float floatx4;

__device__ inline unsigned short rne_bf16(float f) {
    unsigned int u = __float_as_uint(f);
    u += 0x7fffu + ((u >> 16) & 1u);
    return (unsigned short)(u >> 16);
}

__device__ inline int quarter_of(int c) {
    return (c >= 2 * QW) ? ((c >= 3 * QW) ? 3 : 2) : ((c >= QW) ? 1 : 0);
}

// ---------- merged: scatter_bin (blocks 0..390) + cast_x + cast_w ----------
// Staged record: (meta, w_bits), meta = key10<<16 | col16,
// key10 = (row&255)*4 + quarter (global bin = bucket*1024 + key10 = row*4+q).
__global__ __launch_bounds__(512) void prep_bin_kernel(
    const float* __restrict__ x, unsigned short* __restrict__ x_hi,
    const float* __restrict__ W0, const float* __restrict__ W1,
    const float* __restrict__ W2,
    unsigned short* __restrict__ h0, unsigned short* __restrict__ l0,
    unsigned short* __restrict__ h1, unsigned short* __restrict__ l1,
    unsigned short* __restrict__ h2, unsigned short* __restrict__ l2,
    int n4,
    const int* __restrict__ row, const int* __restrict__ col,
    const float* __restrict__ ew, int* __restrict__ scnt,
    int* __restrict__ novf, int4* __restrict__ ovf,
    int2* __restrict__ stage, int E) {
    __shared__ int cnt[NBUCK];
    __shared__ int base[NBUCK];
    __shared__ int gb[NBUCK];
    __shared__ int scn[256];
    __shared__ int2 sdata[CH];
    __shared__ unsigned char sbkt[CH];
    int b = blockIdx.x;
    int tid = threadIdx.x;

    if (b >= BINBLK) {
        int bb = b - BINBLK;
        if (bb < XBLK) {
            int i = bb * 512 + tid;
            if (i < n4) {
                float4 v = reinterpret_cast<const float4*>(x)[i];
                ushort4 o;
                o.x = rne_bf16(v.x); o.y = rne_bf16(v.y);
                o.z = rne_bf16(v.z); o.w = rne_bf16(v.w);
                reinterpret_cast<ushort4*>(x_hi)[i] = o;
            }
        } else {
            int i = (bb - XBLK) * 512 + tid;
            const float* w; unsigned short *hi, *lo; int sidx, didx;
            if (i < 32768)      { w = W0; hi = h0; lo = l0; sidx = i; didx = i; }
            else if (i < 65536) { w = W1; hi = h1; lo = l1; sidx = i - 32768; didx = sidx; }
            else if (i < 81920) {
                w = W2; hi = h2; lo = l2;
                int i2 = i - 65536;            // 0..16383 over Wcat 128x128
                int r = i2 >> 7, k = i2 & 127;
                sidx = (r < 64) ? (r * 256 + k) : ((r - 64) * 256 + 128 + k);
                didx = i2;
            }
            else return;
            float f = w[sidx];
            unsigned short h = rne_bf16(f);
            float fh = __uint_as_float(((unsigned int)h) << 16);
            hi[didx] = h;
            lo[didx] = rne_bf16(f - fh);
        }
        return;
    }

    // ---- scatter_bin body (b in [0, BINBLK)) ----
    for (int i = tid; i < NBUCK; i += 512) cnt[i] = 0;
    __syncthreads();

    int e0 = b * CH + tid * 4;              // E%4==0: quads never straddle E
    int rw4[4], c4[4], w4[4], b4[4], lo4[4];
    bool act = (e0 < E);
    if (act) {
        int4 r = *reinterpret_cast<const int4*>(row + e0);
        int4 c = *reinterpret_cast<const int4*>(col + e0);
        float4 w = *reinterpret_cast<const float4*>(ew + e0);
        rw4[0] = r.x; rw4[1] = r.y; rw4[2] = r.z; rw4[3] = r.w;
        c4[0] = c.x; c4[1] = c.y; c4[2] = c.z; c4[3] = c.w;
        w4[0] = __float_as_int(w.x); w4[1] = __float_as_int(w.y);
        w4[2] = __float_as_int(w.z); w4[3] = __float_as_int(w.w);
#pragma unroll
        for (int u = 0; u < 4; u++) {
            b4[u] = rw4[u] >> 8;
            lo4[u] = atomicAdd(&cnt[b4[u]], 1);
        }
    }
    __syncthreads();

    // exclusive scan of cnt over 256-wide Hillis-Steele
    if (tid < 256) scn[tid] = (tid < NBUCK) ? cnt[tid] : 0;
    __syncthreads();
    for (int off = 1; off < 256; off <<= 1) {
        int t = (tid >= off && tid < 256) ? scn[tid - off] : 0;
        __syncthreads();
        if (tid < 256) scn[tid] += t;
        __syncthreads();
    }
    if (tid < NBUCK) {
        base[tid] = scn[tid] - cnt[tid];
        gb[tid] = (cnt[tid] > 0) ? atomicAdd(&scnt[tid], cnt[tid]) : 0;
    }
    __syncthreads();

    if (act) {
#pragma unroll
        for (int u = 0; u < 4; u++) {
            int slot = base[b4[u]] + lo4[u];
            int key = ((rw4[u] & 255) << 2) | quarter_of(c4[u]);
            sdata[slot] = make_int2((key << 16) | c4[u], w4[u]);
            sbkt[slot] = (unsigned char)b4[u];
        }
    }
    __syncthreads();

    int total = scn[255];
    for (int i = tid; i < total; i += 512) {
        int bk = sbkt[i];
        int2 rec = sdata[i];
        int pos = gb[bk] + (i - base[bk]);
        if (pos < SCAP) {
            stage[bk * SCAP + pos] = rec;
        } else {
            // overflow fallback: tiny global list (never taken for this input)
            int idx = atomicAdd(novf, 1);
            if (idx < OCAP)
                ovf[idx] = make_int4((bk << 10) | ((unsigned int)rec.x >> 16),
                                     rec.x & 0xFFFF, rec.y, 0);
        }
    }
}

// ---------- phase 2: inline bucketBase reduce + per-bucket LDS hist/scan ->
// rowptr + cursors; scatter ----------
__global__ __launch_bounds__(512) void scatter_drain(
    const int2* __restrict__ stage, const int* __restrict__ scnt,
    const int* __restrict__ novf_p, const int4* __restrict__ ovf,
    int* __restrict__ rowptr, int2* __restrict__ ep, int NB, int E) {
    __shared__ int hist[1024];
    __shared__ int s[512];
    int b = blockIdx.x;
    int tid = threadIdx.x;

    // bucketBase[b] = sum of scnt[0..b): 256-wide tree reduce
    if (tid < 256) s[tid] = (tid < b) ? scnt[tid] : 0;
    __syncthreads();
    for (int off = 128; off > 0; off >>= 1) {
        if (tid < off) s[tid] += s[tid + off];
        __syncthreads();
    }
    int bucketBase = s[0];
    if (b == 0 && tid == 0) rowptr[NB] = E;
    __syncthreads();

    for (int i = tid; i < 1024; i += 512) hist[i] = 0;
    __syncthreads();

    int m = scnt[b]; if (m > SCAP) m = SCAP;
    for (int i = tid; i < m; i += 512) {
        int2 rec = stage[b * SCAP + i];
        atomicAdd(&hist[(unsigned int)rec.x >> 16], 1);
    }
    int nov = *novf_p; if (nov > OCAP) nov = OCAP;
    for (int i = tid; i < nov; i += 512) {
        int4 r = ovf[i];
        if ((r.x >> 10) == b) atomicAdd(&hist[r.x & 1023], 1);
    }
    __syncthreads();

    // exclusive scan of 1024 bins: pair-sums + 512-wide Hillis-Steele
    int a0 = hist[2 * tid], a1 = hist[2 * tid + 1];
    s[tid] = a0 + a1;
    __syncthreads();
    for (int off = 1; off < 512; off <<= 1) {
        int t = (tid >= off) ? s[tid - off] : 0;
        __syncthreads();
        s[tid] += t;
        __syncthreads();
    }
    int P = s[tid] - (a0 + a1);            // records with key < 2*tid
    int e0 = bucketBase + P;
    int e1 = e0 + a0;
    hist[2 * tid] = e0;                    // repurpose hist as cursor array
    hist[2 * tid + 1] = e1;
    int g0 = (b << 10) + 2 * tid;
    if (g0 < NB)     rowptr[g0] = e0;
    if (g0 + 1 < NB) rowptr[g0 + 1] = e1;
    __syncthreads();

    for (int i = tid; i < m; i += 512) {
        int2 rec = stage[b * SCAP + i];
        int key = (unsigned int)rec.x >> 16;
        int p = atomicAdd(&hist[key], 1);
        ep[p] = make_int2(rec.x & 0xFFFF, rec.y);
    }
    for (int i = tid; i < nov; i += 512) {
        int4 r = ovf[i];
        if ((r.x >> 10) == b) {
            int p = atomicAdd(&hist[r.x & 1023], 1);
            ep[p] = make_int2(r.y, r.z);
        }
    }
}

// ---------- accum helper ----------
__device__ inline void accum8(float* acc, uint4 a, float w) {
    acc[0] += __uint_as_float(a.x << 16) * w;
    acc[1] += __uint_as_float(a.x & 0xffff0000u) * w;
    acc[2] += __uint_as_float(a.y << 16) * w;
    acc[3] += __uint_as_float(a.y & 0xffff0000u) * w;
    acc[4] += __uint_as_float(a.z << 16) * w;
    acc[5] += __uint_as_float(a.z & 0xffff0000u) * w;
    acc[6] += __uint_as_float(a.w << 16) * w;
    acc[7] += __uint_as_float(a.w & 0xffff0000u) * w;
}

// process edge range [beg,end) for one node; LD = row stride in shorts
template<int LD>
__device__ inline void gather_range(const unsigned short* __restrict__ src,
                                    const int2* __restrict__ ep,
                                    int beg, int end, int fl,
                                    float* acc, float& ds) {
    int e = beg;
    for (; e + 7 < end; e += 8) {
        int2 p[8];
#pragma unroll
        for (int u = 0; u < 8; u++) p[u] = ep[e + u];
        uint4 a[8];
#pragma unroll
        for (int u = 0; u < 8; u++)
            a[u] = *reinterpret_cast<const uint4*>(src + (size_t)p[u].x * LD + fl * 8);
#pragma unroll
        for (int u = 0; u < 8; u++) {
            float w = __int_as_float(p[u].y);
            accum8(acc, a[u], w);
            ds += w;
        }
    }
    for (; e + 3 < end; e += 4) {
        int2 p[4];
#pragma unroll
        for (int u = 0; u < 4; u++) p[u] = ep[e + u];
#pragma unroll
        for (int u = 0; u < 4; u++) {
            uint4 a = *reinterpret_cast<const uint4*>(src + (size_t)p[u].x * LD + fl * 8);
            float w = __int_as_float(p[u].y);
            accum8(acc, a, w);
            ds += w;
        }
    }
    for (; e < end; ++e) {
        int2 p = ep[e];
        uint4 a = *reinterpret_cast<const uint4*>(src + (size_t)p.x * LD + fl * 8);
        float w = __int_as_float(p.y);
        accum8(acc, a, w);
        ds += w;
    }
}

// ---------- gather aggregation, XCD-staggered quarter order (layers 0/1) ----------
__global__ void gather_agg_bf(const unsigned short* __restrict__ src, const int* __restrict__ rowptr4,
                              const int2* __restrict__ ep, unsigned short* __restrict__ agg, int N) {
    long long t = (long long)blockIdx.x * blockDim.x + threadIdx.x;
    int wid = (int)(t >> 6);
    int lane = threadIdx.x & 63;
    int slot = lane >> 4;
    int fl = lane & 15;
    int n = wid * 4 + slot;
    if (n >= N) return;
    int q0 = blockIdx.x & 3;               // XCD-affine start quarter
    int bstart = rowptr4[n * 4];
    int bq = rowptr4[n * 4 + q0];
    int bend = rowptr4[n * 4 + 4];
    float acc[8];
#pragma unroll
    for (int j = 0; j < 8; j++) acc[j] = 0.f;
    float ds = 0.f;
    gather_range<D>(src, ep, bq, bend, fl, acc, ds);      // quarters [q0, 4)
    gather_range<D>(src, ep, bstart, bq, fl, acc, ds);    // quarters [0, q0)
    float inv = 1.0f / (ds > 1.f ? ds : 1.f);
    uint4 o;
    o.x = (unsigned int)rne_bf16(acc[0] * inv) | ((unsigned int)rne_bf16(acc[1] * inv) << 16);
    o.y = (unsigned int)rne_bf16(acc[2] * inv) | ((unsigned int)rne_bf16(acc[3] * inv) << 16);
    o.z = (unsigned int)rne_bf16(acc[4] * inv) | ((unsigned int)rne_bf16(acc[5] * inv) << 16);
    o.w = (unsigned int)rne_bf16(acc[6] * inv) | ((unsigned int)rne_bf16(acc[7] * inv) << 16);
    *reinterpret_cast<uint4*>(agg + (size_t)n * D + fl * 8) = o;
}

// ---------- MFMA GEMM, whole-K W slice in LDS, one barrier (layers 0/1) ----------
template<bool RELU, bool BF16OUT, int OSTRIDE>
__global__ __launch_bounds__(256) void sage_gemm(
    const unsigned short* __restrict__ src, const unsigned short* __restrict__ agg,
    const unsigned short* __restrict__ Whi, const unsigned short* __restrict__ Wlo,
    const float* __restrict__ bias, float* __restrict__ outf,
    unsigned short* __restrict__ outb, int N) {
    __shared__ short sW[2][32][260];
    int tid = threadIdx.x;
    int c0 = blockIdx.y * 32;

    for (int i = tid; i < 2048; i += 256) {
        int h = i >> 10;
        int rem = i & 1023;
        int r = rem & 31;
        int k8 = rem >> 5;
        const unsigned short* wp = (h ? Wlo : Whi) + (size_t)(c0 + r) * K2 + k8 * 8;
        *reinterpret_cast<uint4*>(&sW[h][r][k8 * 8]) = *reinterpret_cast<const uint4*>(wp);
    }
    __syncthreads();

    int lane = tid & 63;
    int wv = tid >> 6;
    int nlane = lane & 15;
    int quad = lane >> 4;
    int m0 = blockIdx.x * 128 + wv * 32;
    int r0 = m0 + nlane;      if (r0 >= N) r0 = N - 1;   // clamped; stores guarded
    int r1 = m0 + 16 + nlane; if (r1 >= N) r1 = N - 1;

    short8 a[2][8];
#pragma unroll
    for (int ks = 0; ks < 8; ks++) {
        int k0 = ks * 32;
        const unsigned short* p0 = (k0 < D) ? (src + (size_t)r0 * D + k0)
                                            : (agg + (size_t)r0 * D + (k0 - D));
        const unsigned short* p1 = (k0 < D) ? (src + (size_t)r1 * D + k0)
                                            : (agg + (size_t)r1 * D + (k0 - D));
        a[0][ks] = *reinterpret_cast<const short8*>(p0 + quad * 8);
        a[1][ks] = *reinterpret_cast<const short8*>(p1 + quad * 8);
    }

    floatx4 acc[2][2];
#pragma unroll
    for (int mt = 0; mt < 2; mt++)
#pragma unroll
        for (int nt = 0; nt < 2; nt++) acc[mt][nt] = (floatx4){0.f, 0.f, 0.f, 0.f};

#pragma unroll
    for (int ks = 0; ks < 8; ks++) {
        int k0 = ks * 32;
#pragma unroll
        for (int nt = 0; nt < 2; nt++) {
            short8 bh = *reinterpret_cast<const short8*>(&sW[0][nt * 16 + nlane][k0 + quad * 8]);
            short8 bl = *reinterpret_cast<const short8*>(&sW[1][nt * 16 + nlane][k0 + quad * 8]);
            acc[0][nt] = __builtin_amdgcn_mfma_f32_16x16x32_bf16(a[0][ks], bh, acc[0][nt], 0, 0, 0);
            acc[0][nt] = __builtin_amdgcn_mfma_f32_16x16x32_bf16(a[0][ks], bl, acc[0][nt], 0, 0, 0);
            acc[1][nt] = __builtin_amdgcn_mfma_f32_16x16x32_bf16(a[1][ks], bh, acc[1][nt], 0, 0, 0);
            acc[1][nt] = __builtin_amdgcn_mfma_f32_16x16x32_bf16(a[1][ks], bl, acc[1][nt], 0, 0, 0);
        }
    }

#pragma unroll
    for (int nt = 0; nt < 2; nt++) {
        int c = c0 + nt * 16 + nlane;
        float bb = bias[c];
#pragma unroll
        for (int mt = 0; mt < 2; mt++) {
#pragma unroll
            for (int r = 0; r < 4; r++) {
                int node = m0 + mt * 16 + quad * 4 + r;
                if (node < N) {
                    float y = acc[mt][nt][r] + bb;
                    if (RELU) y = y > 0.f ? y : 0.f;
                    if (BF16OUT) outb[(size_t)node * OSTRIDE + c] = rne_bf16(y);
                    else         outf[(size_t)node * OSTRIDE + c] = y;
                }
            }
        }
    }
}

// ---------- layer-2 GEMM (K=128): ytop2 = h1@Wtop^T + b2 (fp32), z2 = h1@Wbot^T (bf16)
__global__ __launch_bounds__(256) void sage_gemm2(
    const unsigned short* __restrict__ h1, const unsigned short* __restrict__ Whi,
    const unsigned short* __restrict__ Wlo, const float* __restrict__ b2,
    float* __restrict__ ytop2, unsigned short* __restrict__ z2, int N) {
    __shared__ short sW[2][32][132];    // stride 132 shorts = 66 words = 2 mod 32
    int tid = threadIdx.x;
    int c0 = blockIdx.y * 32;

    for (int i = tid; i < 1024; i += 256) {
        int h = i >> 9;
        int rem = i & 511;
        int r = rem & 31;
        int k8 = rem >> 5;
        const unsigned short* wp = (h ? Wlo : Whi) + (size_t)(c0 + r) * 128 + k8 * 8;
        *reinterpret_cast<uint4*>(&sW[h][r][k8 * 8]) = *reinterpret_cast<const uint4*>(wp);
    }
    __syncthreads();

    int lane = tid & 63;
    int wv = tid >> 6;
    int nlane = lane & 15;
    int quad = lane >> 4;
    int m0 = blockIdx.x * 128 + wv * 32;
    int r0 = m0 + nlane;      if (r0 >= N) r0 = N - 1;
    int r1 = m0 + 16 + nlane; if (r1 >= N) r1 = N - 1;

    short8 a[2][4];
#pragma unroll
    for (int ks = 0; ks < 4; ks++) {
        a[0][ks] = *reinterpret_cast<const short8*>(h1 + (size_t)r0 * D + ks * 32 + quad * 8);
        a[1][ks] = *reinterpret_cast<const short8*>(h1 + (size_t)r1 * D + ks * 32 + quad * 8);
    }

    floatx4 acc[2][2];
#pragma unroll
    for (int mt = 0; mt < 2; mt++)
#pragma unroll
        for (int nt = 0; nt < 2; nt++) acc[mt][nt] = (floatx4){0.f, 0.f, 0.f, 0.f};

#pragma unroll
    for (int ks = 0; ks < 4; ks++) {
        int k0 = ks * 32;
#pragma unroll
        for (int nt = 0; nt < 2; nt++) {
            short8 bh = *reinterpret_cast<const short8*>(&sW[0][nt * 16 + nlane][k0 + quad * 8]);
            short8 bl = *reinterpret_cast<const short8*>(&sW[1][nt * 16 + nlane][k0 + quad * 8]);
            acc[0][nt] = __builtin_amdgcn_mfma_f32_16x16x32_bf16(a[0][ks], bh, acc[0][nt], 0, 0, 0);
            acc[0][nt] = __builtin_amdgcn_mfma_f32_16x16x32_bf16(a[0][ks], bl, acc[0][nt], 0, 0, 0);
            acc[1][nt] = __builtin_amdgcn_mfma_f32_16x16x32_bf16(a[1][ks], bh, acc[1][nt], 0, 0, 0);
            acc[1][nt] = __builtin_amdgcn_mfma_f32_16x16x32_bf16(a[1][ks], bl, acc[1][nt], 0, 0, 0);
        }
    }

#pragma unroll
    for (int nt = 0; nt < 2; nt++) {
        int c = c0 + nt * 16 + nlane;
#pragma unroll
        for (int mt = 0; mt < 2; mt++) {
#pragma unroll
            for (int r = 0; r < 4; r++) {
                int node = m0 + mt * 16 + quad * 4 + r;
                if (node < N) {
                    float v = acc[mt][nt][r];
                    if (c < 64) ytop2[(size_t)node * 64 + c] = v + b2[c];
                    else        z2[(size_t)node * 64 + (c - 64)] = rne_bf16(v);
                }
            }
        }
    }
}

// ---------- layer-2 gather, XCD-staggered quarter order ----------
__global__ void gather_out(const unsigned short* __restrict__ z2, const int* __restrict__ rowptr4,
                           const int2* __restrict__ ep, const float* __restrict__ ytop2,
                           float* __restrict__ out, int N) {
    long long t = (long long)blockIdx.x * blockDim.x + threadIdx.x;
    int wid = (int)(t >> 6);
    int lane = threadIdx.x & 63;
    int slot = lane >> 3;
    int fl = lane & 7;
    int n = wid * 8 + slot;
    if (n >= N) return;
    int q0 = blockIdx.x & 3;               // XCD-affine start quarter
    int bstart = rowptr4[n * 4];
    int bq = rowptr4[n * 4 + q0];
    int bend = rowptr4[n * 4 + 4];
    float acc[8];
#pragma unroll
    for (int j = 0; j < 8; j++) acc[j] = 0.f;
    float ds = 0.f;
    gather_range<64>(z2, ep, bq, bend, fl, acc, ds);
    gather_range<64>(z2, ep, bstart, bq, fl, acc, ds);
    float inv = 1.0f / (ds > 1.f ? ds : 1.f);
    const float* yt = ytop2 + (size_t)n * 64 + fl * 8;
    float* op = out + (size_t)n * 64 + fl * 8;
    float4 t0 = *reinterpret_cast<const float4*>(yt);
    float4 t1 = *reinterpret_cast<const float4*>(yt + 4);
    float4 o0 = make_float4(t0.x + acc[0] * inv, t0.y + acc[1] * inv,
                            t0.z + acc[2] * inv, t0.w + acc[3] * inv);
    float4 o1 = make_float4(t1.x + acc[4] * inv, t1.y + acc[5] * inv,
                            t1.z + acc[6] * inv, t1.w + acc[7] * inv);
    *reinterpret_cast<float4*>(op) = o0;
    *reinterpret_cast<float4*>(op + 4) = o1;
}

extern "C" void kernel_launch(void* const* d_in, const int* in_sizes, int n_in,
                              void* d_out, int out_size, void* d_ws, size_t ws_size,
                              hipStream_t stream) {
    const float* x  = (const float*)d_in[0];
    const int*   ei = (const int*)d_in[1];
    const float* ew = (const float*)d_in[2];
    const float* W0 = (const float*)d_in[3];
    const float* b0 = (const float*)d_in[4];
    const float* W1 = (const float*)d_in[5];
    const float* b1 = (const float*)d_in[6];
    const float* W2 = (const float*)d_in[7];
    const float* b2 = (const float*)d_in[8];
    float* out = (float*)d_out;

    const int N = 50000;
    const int E = in_sizes[2];          // 800000
    const int NB = N * NQ;              // 200000 bins
    const int* row = ei;
    const int* col = ei + E;

    char* base = (char*)d_ws;
    size_t ND = (size_t)N * D;
    unsigned short* x_hi   = (unsigned short*)base;               base += ND * 2;
    unsigned short* h0_hi  = (unsigned short*)base;               base += ND * 2;
    unsigned short* h1_hi  = (unsigned short*)base;               base += ND * 2;
    unsigned short* agg_hi = (unsigned short*)base;               base += ND * 2;
    int2* ep               = (int2*)base;                         base += (size_t)E * 8;
    int* rowptr4           = (int*)base;                          base += (size_t)(NB + 1) * 4;
    unsigned short* W0hi   = (unsigned short*)base;               base += 128 * 256 * 2;
    unsigned short* W0lo   = (unsigned short*)base;               base += 128 * 256 * 2;
    unsigned short* W1hi   = (unsigned short*)base;               base += 128 * 256 * 2;
    unsigned short* W1lo   = (unsigned short*)base;               base += 128 * 256 * 2;
    unsigned short* W2Chi  = (unsigned short*)base;               base += 128 * 128 * 2;
    unsigned short* W2Clo  = (unsigned short*)base;               base += 128 * 128 * 2;

    // CSR scratch aliases h0_hi (dead until layer-0 GEMM writes it)
    int* scnt = (int*)h0_hi;                    // 256 ints (196 used)
    int* novf = scnt + 256;                     // 1 int
    int4* ovf = (int4*)(scnt + 1024);           // OCAP*16B = 128KB

    // staging aliases h1_hi (dead until layer-1 GEMM writes it): 196*5120*8B = 8.0MB
    int2* stage = (int2*)h1_hi;

    // layer-2 scratch: ytop2 (fp32 N*64 = 12.8MB) aliases agg_hi (free after L1
    // GEMM); z2 (bf16 N*64 = 6.4MB) aliases h0_hi (free after L1 GEMM).
    float* ytop2          = (float*)agg_hi;
    unsigned short* z2    = (unsigned short*)h0_hi;

    // ---- merged prep + bin (memset covers scnt+novf) ----
    hipMemsetAsync(scnt, 0, 2048, stream);
    int n4 = (int)(ND / 4);             // 1,600,000
    prep_bin_kernel<<<BINBLK + XBLK + WBLK, 512, 0, stream>>>(
        x, x_hi, W0, W1, W2, W0hi, W0lo, W1hi, W1lo, W2Chi, W2Clo, n4,
        row, col, ew, scnt, novf, ovf, stage, E);

    // ---- drain (inline bucketBase reduce + CSR build + scatter) ----
    scatter_drain<<<NBUCK, 512, 0, stream>>>(stage, scnt, novf, ovf, rowptr4, ep, NB, E);

    int nWaves = (N + 3) / 4;                       // 12500 (4 nodes/wave)
    int aggBlocks = (int)(((long long)nWaves * 64 + 255) / 256);
    int nodeTiles = (N + 127) / 128;                // 391
    dim3 g128(nodeTiles, 4);                        // OUT=128: four 32-col tiles

    // layer 0: x -> h0
    gather_agg_bf<<<aggBlocks, 256, 0, stream>>>(x_hi, rowptr4, ep, agg_hi, N);
    sage_gemm<true, true, D><<<g128, 256, 0, stream>>>(
        x_hi, agg_hi, W0hi, W0lo, b0, nullptr, h0_hi, N);

    // layer 1: h0 -> h1
    gather_agg_bf<<<aggBlocks, 256, 0, stream>>>(h0_hi, rowptr4, ep, agg_hi, N);
    sage_gemm<true, true, D><<<g128, 256, 0, stream>>>(
        h0_hi, agg_hi, W1hi, W1lo, b1, nullptr, h1_hi, N);

    // layer 2 (z-trick): h1 -> (ytop2, z2) -> out
    sage_gemm2<<<g128, 256, 0, stream>>>(h1_hi, W2Chi, W2Clo, b2, ytop2, z2, N);
    int nWaves2 = (N + 7) / 8;                      // 6250 (8 nodes/wave)
    int outBlocks = (int)(((long long)nWaves2 * 64 + 255) / 256);
    gather_out<<<outBlocks, 256, 0, stream>>>(z2, rowptr4, ep, ytop2, out, N);
}

// Round 13
// 265.437 us; speedup vs baseline: 1.0475x; 1.0475x over previous
//
#include <hip/hip_runtime.h>

// GraphSAGE 3-layer, N=50000, E=800000, D=128, D_OUT=64.
// R24: exact revert to R22 (verified 266.9us). R23's XCD-staggered quarter
// order regressed (-11us): avg degree 16 => ~4 edges/quarter, so the split
// ranges fell out of the 8-wide unroll into scalar tails (+2 rowptr reads).
// Gather theories falsified: ep-latency (R21 neutral), L2-slice-thrash (R23
// regressed). Model: gathers ~5 TB/s on ~512MB random L3 reads ~ fabric rate.
// Structure: merged prep+bin; drain w/ inline CSR build; standalone gathers +
// K=256 MFMA GEMMs; layer-2 z-trick. 8 dispatches.

#define D 128
#define K2 256
#define NQ 4            // col quarters
#define QW 12500        // quarter width (N/4)
#define NBUCK 196       // row buckets (256 rows each)
#define SCAP 5120       // staging capacity per bucket (expected 4081, +16 sigma)
#define OCAP 8192       // overflow list capacity (never reached in practice)
#define CH 2048         // edges per scatter_bin block
#define BINBLK 391      // ceil(E/CH)
#define XBLK 3125       // 1.6M quads / 512
#define WBLK 160        // 81920 / 512

typedef __attribute__((ext_vector_type(8))) short short8;
typedef __attribute__((ext_vector_type(4))) float floatx4;

__device__ inline unsigned short rne_bf16(float f) {
    unsigned int u = __float_as_uint(f);
    u += 0x7fffu + ((u >> 16) & 1u);
    return (unsigned short)(u >> 16);
}

__device__ inline int quarter_of(int c) {
    return (c >= 2 * QW) ? ((c >= 3 * QW) ? 3 : 2) : ((c >= QW) ? 1 : 0);
}

// ---------- merged: scatter_bin (blocks 0..390) + cast_x + cast_w ----------
// Staged record: (meta, w_bits), meta = key10<<16 | col16,
// key10 = (row&255)*4 + quarter (global bin = bucket*1024 + key10 = row*4+q).
__global__ __launch_bounds__(512) void prep_bin_kernel(
    const float* __restrict__ x, unsigned short* __restrict__ x_hi,
    const float* __restrict__ W0, const float* __restrict__ W1,
    const float* __restrict__ W2,
    unsigned short* __restrict__ h0, unsigned short* __restrict__ l0,
    unsigned short* __restrict__ h1, unsigned short* __restrict__ l1,
    unsigned short* __restrict__ h2, unsigned short* __restrict__ l2,
    int n4,
    const int* __restrict__ row, const int* __restrict__ col,
    const float* __restrict__ ew, int* __restrict__ scnt,
    int* __restrict__ novf, int4* __restrict__ ovf,
    int2* __restrict__ stage, int E) {
    __shared__ int cnt[NBUCK];
    __shared__ int base[NBUCK];
    __shared__ int gb[NBUCK];
    __shared__ int scn[256];
    __shared__ int2 sdata[CH];
    __shared__ unsigned char sbkt[CH];
    int b = blockIdx.x;
    int tid = threadIdx.x;

    if (b >= BINBLK) {
        int bb = b - BINBLK;
        if (bb < XBLK) {
            int i = bb * 512 + tid;
            if (i < n4) {
                float4 v = reinterpret_cast<const float4*>(x)[i];
                ushort4 o;
                o.x = rne_bf16(v.x); o.y = rne_bf16(v.y);
                o.z = rne_bf16(v.z); o.w = rne_bf16(v.w);
                reinterpret_cast<ushort4*>(x_hi)[i] = o;
            }
        } else {
            int i = (bb - XBLK) * 512 + tid;
            const float* w; unsigned short *hi, *lo; int sidx, didx;
            if (i < 32768)      { w = W0; hi = h0; lo = l0; sidx = i; didx = i; }
            else if (i < 65536) { w = W1; hi = h1; lo = l1; sidx = i - 32768; didx = sidx; }
            else if (i < 81920) {
                w = W2; hi = h2; lo = l2;
                int i2 = i - 65536;            // 0..16383 over Wcat 128x128
                int r = i2 >> 7, k = i2 & 127;
                sidx = (r < 64) ? (r * 256 + k) : ((r - 64) * 256 + 128 + k);
                didx = i2;
            }
            else return;
            float f = w[sidx];
            unsigned short h = rne_bf16(f);
            float fh = __uint_as_float(((unsigned int)h) << 16);
            hi[didx] = h;
            lo[didx] = rne_bf16(f - fh);
        }
        return;
    }

    // ---- scatter_bin body (b in [0, BINBLK)) ----
    for (int i = tid; i < NBUCK; i += 512) cnt[i] = 0;
    __syncthreads();

    int e0 = b * CH + tid * 4;              // E%4==0: quads never straddle E
    int rw4[4], c4[4], w4[4], b4[4], lo4[4];
    bool act = (e0 < E);
    if (act) {
        int4 r = *reinterpret_cast<const int4*>(row + e0);
        int4 c = *reinterpret_cast<const int4*>(col + e0);
        float4 w = *reinterpret_cast<const float4*>(ew + e0);
        rw4[0] = r.x; rw4[1] = r.y; rw4[2] = r.z; rw4[3] = r.w;
        c4[0] = c.x; c4[1] = c.y; c4[2] = c.z; c4[3] = c.w;
        w4[0] = __float_as_int(w.x); w4[1] = __float_as_int(w.y);
        w4[2] = __float_as_int(w.z); w4[3] = __float_as_int(w.w);
#pragma unroll
        for (int u = 0; u < 4; u++) {
            b4[u] = rw4[u] >> 8;
            lo4[u] = atomicAdd(&cnt[b4[u]], 1);
        }
    }
    __syncthreads();

    // exclusive scan of cnt over 256-wide Hillis-Steele
    if (tid < 256) scn[tid] = (tid < NBUCK) ? cnt[tid] : 0;
    __syncthreads();
    for (int off = 1; off < 256; off <<= 1) {
        int t = (tid >= off && tid < 256) ? scn[tid - off] : 0;
        __syncthreads();
        if (tid < 256) scn[tid] += t;
        __syncthreads();
    }
    if (tid < NBUCK) {
        base[tid] = scn[tid] - cnt[tid];
        gb[tid] = (cnt[tid] > 0) ? atomicAdd(&scnt[tid], cnt[tid]) : 0;
    }
    __syncthreads();

    if (act) {
#pragma unroll
        for (int u = 0; u < 4; u++) {
            int slot = base[b4[u]] + lo4[u];
            int key = ((rw4[u] & 255) << 2) | quarter_of(c4[u]);
            sdata[slot] = make_int2((key << 16) | c4[u], w4[u]);
            sbkt[slot] = (unsigned char)b4[u];
        }
    }
    __syncthreads();

    int total = scn[255];
    for (int i = tid; i < total; i += 512) {
        int bk = sbkt[i];
        int2 rec = sdata[i];
        int pos = gb[bk] + (i - base[bk]);
        if (pos < SCAP) {
            stage[bk * SCAP + pos] = rec;
        } else {
            // overflow fallback: tiny global list (never taken for this input)
            int idx = atomicAdd(novf, 1);
            if (idx < OCAP)
                ovf[idx] = make_int4((bk << 10) | ((unsigned int)rec.x >> 16),
                                     rec.x & 0xFFFF, rec.y, 0);
        }
    }
}

// ---------- phase 2: inline bucketBase reduce + per-bucket LDS hist/scan ->
// rowptr + cursors; scatter ----------
__global__ __launch_bounds__(512) void scatter_drain(
    const int2* __restrict__ stage, const int* __restrict__ scnt,
    const int* __restrict__ novf_p, const int4* __restrict__ ovf,
    int* __restrict__ rowptr, int2* __restrict__ ep, int NB, int E) {
    __shared__ int hist[1024];
    __shared__ int s[512];
    int b = blockIdx.x;
    int tid = threadIdx.x;

    // bucketBase[b] = sum of scnt[0..b): 256-wide tree reduce
    if (tid < 256) s[tid] = (tid < b) ? scnt[tid] : 0;
    __syncthreads();
    for (int off = 128; off > 0; off >>= 1) {
        if (tid < off) s[tid] += s[tid + off];
        __syncthreads();
    }
    int bucketBase = s[0];
    if (b == 0 && tid == 0) rowptr[NB] = E;
    __syncthreads();

    for (int i = tid; i < 1024; i += 512) hist[i] = 0;
    __syncthreads();

    int m = scnt[b]; if (m > SCAP) m = SCAP;
    for (int i = tid; i < m; i += 512) {
        int2 rec = stage[b * SCAP + i];
        atomicAdd(&hist[(unsigned int)rec.x >> 16], 1);
    }
    int nov = *novf_p; if (nov > OCAP) nov = OCAP;
    for (int i = tid; i < nov; i += 512) {
        int4 r = ovf[i];
        if ((r.x >> 10) == b) atomicAdd(&hist[r.x & 1023], 1);
    }
    __syncthreads();

    // exclusive scan of 1024 bins: pair-sums + 512-wide Hillis-Steele
    int a0 = hist[2 * tid], a1 = hist[2 * tid + 1];
    s[tid] = a0 + a1;
    __syncthreads();
    for (int off = 1; off < 512; off <<= 1) {
        int t = (tid >= off) ? s[tid - off] : 0;
        __syncthreads();
        s[tid] += t;
        __syncthreads();
    }
    int P = s[tid] - (a0 + a1);            // records with key < 2*tid
    int e0 = bucketBase + P;
    int e1 = e0 + a0;
    hist[2 * tid] = e0;                    // repurpose hist as cursor array
    hist[2 * tid + 1] = e1;
    int g0 = (b << 10) + 2 * tid;
    if (g0 < NB)     rowptr[g0] = e0;
    if (g0 + 1 < NB) rowptr[g0 + 1] = e1;
    __syncthreads();

    for (int i = tid; i < m; i += 512) {
        int2 rec = stage[b * SCAP + i];
        int key = (unsigned int)rec.x >> 16;
        int p = atomicAdd(&hist[key], 1);
        ep[p] = make_int2(rec.x & 0xFFFF, rec.y);
    }
    for (int i = tid; i < nov; i += 512) {
        int4 r = ovf[i];
        if ((r.x >> 10) == b) {
            int p = atomicAdd(&hist[r.x & 1023], 1);
            ep[p] = make_int2(r.y, r.z);
        }
    }
}

// ---------- accum helper ----------
__device__ inline void accum8(float* acc, uint4 a, float w) {
    acc[0] += __uint_as_float(a.x << 16) * w;
    acc[1] += __uint_as_float(a.x & 0xffff0000u) * w;
    acc[2] += __uint_as_float(a.y << 16) * w;
    acc[3] += __uint_as_float(a.y & 0xffff0000u) * w;
    acc[4] += __uint_as_float(a.z << 16) * w;
    acc[5] += __uint_as_float(a.z & 0xffff0000u) * w;
    acc[6] += __uint_as_float(a.w << 16) * w;
    acc[7] += __uint_as_float(a.w & 0xffff0000u) * w;
}

// ---------- gather aggregation (bf16 src/dst), unroll x8 (layers 0/1) ----------
__global__ void gather_agg_bf(const unsigned short* __restrict__ src, const int* __restrict__ rowptr4,
                              const int2* __restrict__ ep, unsigned short* __restrict__ agg, int N) {
    long long t = (long long)blockIdx.x * blockDim.x + threadIdx.x;
    int wid = (int)(t >> 6);
    int lane = threadIdx.x & 63;
    int slot = lane >> 4;
    int fl = lane & 15;
    int n = wid * 4 + slot;
    if (n >= N) return;
    int beg = rowptr4[n * 4], end = rowptr4[n * 4 + 4];
    float acc[8];
#pragma unroll
    for (int j = 0; j < 8; j++) acc[j] = 0.f;
    float ds = 0.f;
    int e = beg;
    for (; e + 7 < end; e += 8) {
        int2 p[8];
#pragma unroll
        for (int u = 0; u < 8; u++) p[u] = ep[e + u];
        uint4 a[8];
#pragma unroll
        for (int u = 0; u < 8; u++)
            a[u] = *reinterpret_cast<const uint4*>(src + (size_t)p[u].x * D + fl * 8);
#pragma unroll
        for (int u = 0; u < 8; u++) {
            float w = __int_as_float(p[u].y);
            accum8(acc, a[u], w);
            ds += w;
        }
    }
    for (; e + 3 < end; e += 4) {
        int2 p[4];
#pragma unroll
        for (int u = 0; u < 4; u++) p[u] = ep[e + u];
#pragma unroll
        for (int u = 0; u < 4; u++) {
            uint4 a = *reinterpret_cast<const uint4*>(src + (size_t)p[u].x * D + fl * 8);
            float w = __int_as_float(p[u].y);
            accum8(acc, a, w);
            ds += w;
        }
    }
    for (; e < end; ++e) {
        int2 p = ep[e];
        uint4 a = *reinterpret_cast<const uint4*>(src + (size_t)p.x * D + fl * 8);
        float w = __int_as_float(p.y);
        accum8(acc, a, w);
        ds += w;
    }
    float inv = 1.0f / (ds > 1.f ? ds : 1.f);
    uint4 o;
    o.x = (unsigned int)rne_bf16(acc[0] * inv) | ((unsigned int)rne_bf16(acc[1] * inv) << 16);
    o.y = (unsigned int)rne_bf16(acc[2] * inv) | ((unsigned int)rne_bf16(acc[3] * inv) << 16);
    o.z = (unsigned int)rne_bf16(acc[4] * inv) | ((unsigned int)rne_bf16(acc[5] * inv) << 16);
    o.w = (unsigned int)rne_bf16(acc[6] * inv) | ((unsigned int)rne_bf16(acc[7] * inv) << 16);
    *reinterpret_cast<uint4*>(agg + (size_t)n * D + fl * 8) = o;
}

// ---------- MFMA GEMM, whole-K W slice in LDS, one barrier (layers 0/1) ----------
template<bool RELU, bool BF16OUT, int OSTRIDE>
__global__ __launch_bounds__(256) void sage_gemm(
    const unsigned short* __restrict__ src, const unsigned short* __restrict__ agg,
    const unsigned short* __restrict__ Whi, const unsigned short* __restrict__ Wlo,
    const float* __restrict__ bias, float* __restrict__ outf,
    unsigned short* __restrict__ outb, int N) {
    __shared__ short sW[2][32][260];
    int tid = threadIdx.x;
    int c0 = blockIdx.y * 32;

    for (int i = tid; i < 2048; i += 256) {
        int h = i >> 10;
        int rem = i & 1023;
        int r = rem & 31;
        int k8 = rem >> 5;
        const unsigned short* wp = (h ? Wlo : Whi) + (size_t)(c0 + r) * K2 + k8 * 8;
        *reinterpret_cast<uint4*>(&sW[h][r][k8 * 8]) = *reinterpret_cast<const uint4*>(wp);
    }
    __syncthreads();

    int lane = tid & 63;
    int wv = tid >> 6;
    int nlane = lane & 15;
    int quad = lane >> 4;
    int m0 = blockIdx.x * 128 + wv * 32;
    int r0 = m0 + nlane;      if (r0 >= N) r0 = N - 1;   // clamped; stores guarded
    int r1 = m0 + 16 + nlane; if (r1 >= N) r1 = N - 1;

    short8 a[2][8];
#pragma unroll
    for (int ks = 0; ks < 8; ks++) {
        int k0 = ks * 32;
        const unsigned short* p0 = (k0 < D) ? (src + (size_t)r0 * D + k0)
                                            : (agg + (size_t)r0 * D + (k0 - D));
        const unsigned short* p1 = (k0 < D) ? (src + (size_t)r1 * D + k0)
                                            : (agg + (size_t)r1 * D + (k0 - D));
        a[0][ks] = *reinterpret_cast<const short8*>(p0 + quad * 8);
        a[1][ks] = *reinterpret_cast<const short8*>(p1 + quad * 8);
    }

    floatx4 acc[2][2];
#pragma unroll
    for (int mt = 0; mt < 2; mt++)
#pragma unroll
        for (int nt = 0; nt < 2; nt++) acc[mt][nt] = (floatx4){0.f, 0.f, 0.f, 0.f};

#pragma unroll
    for (int ks = 0; ks < 8; ks++) {
        int k0 = ks * 32;
#pragma unroll
        for (int nt = 0; nt < 2; nt++) {
            short8 bh = *reinterpret_cast<const short8*>(&sW[0][nt * 16 + nlane][k0 + quad * 8]);
            short8 bl = *reinterpret_cast<const short8*>(&sW[1][nt * 16 + nlane][k0 + quad * 8]);
            acc[0][nt] = __builtin_amdgcn_mfma_f32_16x16x32_bf16(a[0][ks], bh, acc[0][nt], 0, 0, 0);
            acc[0][nt] = __builtin_amdgcn_mfma_f32_16x16x32_bf16(a[0][ks], bl, acc[0][nt], 0, 0, 0);
            acc[1][nt] = __builtin_amdgcn_mfma_f32_16x16x32_bf16(a[1][ks], bh, acc[1][nt], 0, 0, 0);
            acc[1][nt] = __builtin_amdgcn_mfma_f32_16x16x32_bf16(a[1][ks], bl, acc[1][nt], 0, 0, 0);
        }
    }

#pragma unroll
    for (int nt = 0; nt < 2; nt++) {
        int c = c0 + nt * 16 + nlane;
        float bb = bias[c];
#pragma unroll
        for (int mt = 0; mt < 2; mt++) {
#pragma unroll
            for (int r = 0; r < 4; r++) {
                int node = m0 + mt * 16 + quad * 4 + r;
                if (node < N) {
                    float y = acc[mt][nt][r] + bb;
                    if (RELU) y = y > 0.f ? y : 0.f;
                    if (BF16OUT) outb[(size_t)node * OSTRIDE + c] = rne_bf16(y);
                    else         outf[(size_t)node * OSTRIDE + c] = y;
                }
            }
        }
    }
}

// ---------- layer-2 GEMM (K=128): ytop2 = h1@Wtop^T + b2 (fp32), z2 = h1@Wbot^T (bf16)
__global__ __launch_bounds__(256) void sage_gemm2(
    const unsigned short* __restrict__ h1, const unsigned short* __restrict__ Whi,
    const unsigned short* __restrict__ Wlo, const float* __restrict__ b2,
    float* __restrict__ ytop2, unsigned short* __restrict__ z2, int N) {
    __shared__ short sW[2][32][132];    // stride 132 shorts = 66 words = 2 mod 32
    int tid = threadIdx.x;
    int c0 = blockIdx.y * 32;

    for (int i = tid; i < 1024; i += 256) {
        int h = i >> 9;
        int rem = i & 511;
        int r = rem & 31;
        int k8 = rem >> 5;
        const unsigned short* wp = (h ? Wlo : Whi) + (size_t)(c0 + r) * 128 + k8 * 8;
        *reinterpret_cast<uint4*>(&sW[h][r][k8 * 8]) = *reinterpret_cast<const uint4*>(wp);
    }
    __syncthreads();

    int lane = tid & 63;
    int wv = tid >> 6;
    int nlane = lane & 15;
    int quad = lane >> 4;
    int m0 = blockIdx.x * 128 + wv * 32;
    int r0 = m0 + nlane;      if (r0 >= N) r0 = N - 1;
    int r1 = m0 + 16 + nlane; if (r1 >= N) r1 = N - 1;

    short8 a[2][4];
#pragma unroll
    for (int ks = 0; ks < 4; ks++) {
        a[0][ks] = *reinterpret_cast<const short8*>(h1 + (size_t)r0 * D + ks * 32 + quad * 8);
        a[1][ks] = *reinterpret_cast<const short8*>(h1 + (size_t)r1 * D + ks * 32 + quad * 8);
    }

    floatx4 acc[2][2];
#pragma unroll
    for (int mt = 0; mt < 2; mt++)
#pragma unroll
        for (int nt = 0; nt < 2; nt++) acc[mt][nt] = (floatx4){0.f, 0.f, 0.f, 0.f};

#pragma unroll
    for (int ks = 0; ks < 4; ks++) {
        int k0 = ks * 32;
#pragma unroll
        for (int nt = 0; nt < 2; nt++) {
            short8 bh = *reinterpret_cast<const short8*>(&sW[0][nt * 16 + nlane][k0 + quad * 8]);
            short8 bl = *reinterpret_cast<const short8*>(&sW[1][nt * 16 + nlane][k0 + quad * 8]);
            acc[0][nt] = __builtin_amdgcn_mfma_f32_16x16x32_bf16(a[0][ks], bh, acc[0][nt], 0, 0, 0);
            acc[0][nt] = __builtin_amdgcn_mfma_f32_16x16x32_bf16(a[0][ks], bl, acc[0][nt], 0, 0, 0);
            acc[1][nt] = __builtin_amdgcn_mfma_f32_16x16x32_bf16(a[1][ks], bh, acc[1][nt], 0, 0, 0);
            acc[1][nt] = __builtin_amdgcn_mfma_f32_16x16x32_bf16(a[1][ks], bl, acc[1][nt], 0, 0, 0);
        }
    }

#pragma unroll
    for (int nt = 0; nt < 2; nt++) {
        int c = c0 + nt * 16 + nlane;
#pragma unroll
        for (int mt = 0; mt < 2; mt++) {
#pragma unroll
            for (int r = 0; r < 4; r++) {
                int node = m0 + mt * 16 + quad * 4 + r;
                if (node < N) {
                    float v = acc[mt][nt][r];
                    if (c < 64) ytop2[(size_t)node * 64 + c] = v + b2[c];
                    else        z2[(size_t)node * 64 + (c - 64)] = rne_bf16(v);
                }
            }
        }
    }
}

// ---------- layer-2 gather: out[n] = ytop2[n] + (sum w*z2[col])/deg ----------
__global__ void gather_out(const unsigned short* __restrict__ z2, const int* __restrict__ rowptr4,
                           const int2* __restrict__ ep, const float* __restrict__ ytop2,
                           float* __restrict__ out, int N) {
    long long t = (long long)blockIdx.x * blockDim.x + threadIdx.x;
    int wid = (int)(t >> 6);
    int lane = threadIdx.x & 63;
    int slot = lane >> 3;
    int fl = lane & 7;
    int n = wid * 8 + slot;
    if (n >= N) return;
    int beg = rowptr4[n * 4], end = rowptr4[n * 4 + 4];
    float acc[8];
#pragma unroll
    for (int j = 0; j < 8; j++) acc[j] = 0.f;
    float ds = 0.f;
    int e = beg;
    for (; e + 7 < end; e += 8) {
        int2 p[8];
#pragma unroll
        for (int u = 0; u < 8; u++) p[u] = ep[e + u];
        uint4 a[8];
#pragma unroll
        for (int u = 0; u < 8; u++)
            a[u] = *reinterpret_cast<const uint4*>(z2 + (size_t)p[u].x * 64 + fl * 8);
#pragma unroll
        for (int u = 0; u < 8; u++) {
            float w = __int_as_float(p[u].y);
            accum8(acc, a[u], w);
            ds += w;
        }
    }
    for (; e < end; ++e) {
        int2 p = ep[e];
        uint4 a = *reinterpret_cast<const uint4*>(z2 + (size_t)p.x * 64 + fl * 8);
        float w = __int_as_float(p.y);
        accum8(acc, a, w);
        ds += w;
    }
    float inv = 1.0f / (ds > 1.f ? ds : 1.f);
    const float* yt = ytop2 + (size_t)n * 64 + fl * 8;
    float* op = out + (size_t)n * 64 + fl * 8;
    float4 t0 = *reinterpret_cast<const float4*>(yt);
    float4 t1 = *reinterpret_cast<const float4*>(yt + 4);
    float4 o0 = make_float4(t0.x + acc[0] * inv, t0.y + acc[1] * inv,
                            t0.z + acc[2] * inv, t0.w + acc[3] * inv);
    float4 o1 = make_float4(t1.x + acc[4] * inv, t1.y + acc[5] * inv,
                            t1.z + acc[6] * inv, t1.w + acc[7] * inv);
    *reinterpret_cast<float4*>(op) = o0;
    *reinterpret_cast<float4*>(op + 4) = o1;
}

extern "C" void kernel_launch(void* const* d_in, const int* in_sizes, int n_in,
                              void* d_out, int out_size, void* d_ws, size_t ws_size,
                              hipStream_t stream) {
    const float* x  = (const float*)d_in[0];
    const int*   ei = (const int*)d_in[1];
    const float* ew = (const float*)d_in[2];
    const float* W0 = (const float*)d_in[3];
    const float* b0 = (const float*)d_in[4];
    const float* W1 = (const float*)d_in[5];
    const float* b1 = (const float*)d_in[6];
    const float* W2 = (const float*)d_in[7];
    const float* b2 = (const float*)d_in[8];
    float* out = (float*)d_out;

    const int N = 50000;
    const int E = in_sizes[2];          // 800000
    const int NB = N * NQ;              // 200000 bins
    const int* row = ei;
    const int* col = ei + E;

    char* base = (char*)d_ws;
    size_t ND = (size_t)N * D;
    unsigned short* x_hi   = (unsigned short*)base;               base += ND * 2;
    unsigned short* h0_hi  = (unsigned short*)base;               base += ND * 2;
    unsigned short* h1_hi  = (unsigned short*)base;               base += ND * 2;
    unsigned short* agg_hi = (unsigned short*)base;               base += ND * 2;
    int2* ep               = (int2*)base;                         base += (size_t)E * 8;
    int* rowptr4           = (int*)base;                          base += (size_t)(NB + 1) * 4;
    unsigned short* W0hi   = (unsigned short*)base;               base += 128 * 256 * 2;
    unsigned short* W0lo   = (unsigned short*)base;               base += 128 * 256 * 2;
    unsigned short* W1hi   = (unsigned short*)base;               base += 128 * 256 * 2;
    unsigned short* W1lo   = (unsigned short*)base;               base += 128 * 256 * 2;
    unsigned short* W2Chi  = (unsigned short*)base;               base += 128 * 128 * 2;
    unsigned short* W2Clo  = (unsigned short*)base;               base += 128 * 128 * 2;

    // CSR scratch aliases h0_hi (dead until layer-0 GEMM writes it)
    int* scnt = (int*)h0_hi;                    // 256 ints (196 used)
    int* novf = scnt + 256;                     // 1 int
    int4* ovf = (int4*)(scnt + 1024);           // OCAP*16B = 128KB

    // staging aliases h1_hi (dead until layer-1 GEMM writes it): 196*5120*8B = 8.0MB
    int2* stage = (int2*)h1_hi;

    // layer-2 scratch: ytop2 (fp32 N*64 = 12.8MB) aliases agg_hi (free after L1
    // GEMM); z2 (bf16 N*64 = 6.4MB) aliases h0_hi (free after L1 GEMM).
    float* ytop2          = (float*)agg_hi;
    unsigned short* z2    = (unsigned short*)h0_hi;

    // ---- merged prep + bin (memset covers scnt+novf) ----
    hipMemsetAsync(scnt, 0, 2048, stream);
    int n4 = (int)(ND / 4);             // 1,600,000
    prep_bin_kernel<<<BINBLK + XBLK + WBLK, 512, 0, stream>>>(
        x, x_hi, W0, W1, W2, W0hi, W0lo, W1hi, W1lo, W2Chi, W2Clo, n4,
        row, col, ew, scnt, novf, ovf, stage, E);

    // ---- drain (inline bucketBase reduce + CSR build + scatter) ----
    scatter_drain<<<NBUCK, 512, 0, stream>>>(stage, scnt, novf, ovf, rowptr4, ep, NB, E);

    int nWaves = (N + 3) / 4;                       // 12500 (4 nodes/wave)
    int aggBlocks = (int)(((long long)nWaves * 64 + 255) / 256);
    int nodeTiles = (N + 127) / 128;                // 391
    dim3 g128(nodeTiles, 4);                        // OUT=128: four 32-col tiles

    // layer 0: x -> h0
    gather_agg_bf<<<aggBlocks, 256, 0, stream>>>(x_hi, rowptr4, ep, agg_hi, N);
    sage_gemm<true, true, D><<<g128, 256, 0, stream>>>(
        x_hi, agg_hi, W0hi, W0lo, b0, nullptr, h0_hi, N);

    // layer 1: h0 -> h1
    gather_agg_bf<<<aggBlocks, 256, 0, stream>>>(h0_hi, rowptr4, ep, agg_hi, N);
    sage_gemm<true, true, D><<<g128, 256, 0, stream>>>(
        h0_hi, agg_hi, W1hi, W1lo, b1, nullptr, h1_hi, N);

    // layer 2 (z-trick): h1 -> (ytop2, z2) -> out
    sage_gemm2<<<g128, 256, 0, stream>>>(h1_hi, W2Chi, W2Clo, b2, ytop2, z2, N);
    int nWaves2 = (N + 7) / 8;                      // 6250 (8 nodes/wave)
    int outBlocks = (int)(((long long)nWaves2 * 64 + 255) / 256);
    gather_out<<<outBlocks, 256, 0, stream>>>(z2, rowptr4, ep, ytop2, out, N);
}